// Round 2
// baseline (1989.019 us; speedup 1.0000x reference)
//
#include <hip/hip_runtime.h>
#include <math.h>

#define F 64
#define WPB 4    // waves per block
#define RPW 16   // rows per wave -> 64 rows per block in prop kernel

static __device__ __forceinline__ ushort f2bf(float f) {
    uint u = __float_as_uint(f);
    uint r = (u + 0x7fffu + ((u >> 16) & 1u)) >> 16;  // RNE
    return (ushort)r;
}
static __device__ __forceinline__ float bf2f(ushort v) {
    return __uint_as_float(((uint)v) << 16);
}

// ---------- CSR build ----------

__global__ __launch_bounds__(256) void deg_kernel(const int* __restrict__ ei, int E,
                                                  int* __restrict__ deg) {
    int e = blockIdx.x * 256 + threadIdx.x;
    if (e >= E) return;
    int r = ei[e], c = ei[E + e];
    if (r != c) atomicAdd(&deg[r], 1);
}

__global__ __launch_bounds__(256) void scan1_kernel(const int* __restrict__ deg,
                                                    int* __restrict__ rp,
                                                    int* __restrict__ bsum, int Nv) {
    __shared__ int sh[256];
    int t = threadIdx.x;
    int base = blockIdx.x * 1024 + t * 4;
    int v0 = (base + 0 < Nv) ? deg[base + 0] : 0;
    int v1 = (base + 1 < Nv) ? deg[base + 1] : 0;
    int v2 = (base + 2 < Nv) ? deg[base + 2] : 0;
    int v3 = (base + 3 < Nv) ? deg[base + 3] : 0;
    int s = v0 + v1 + v2 + v3;
    sh[t] = s;
    __syncthreads();
    for (int off = 1; off < 256; off <<= 1) {
        int a = (t >= off) ? sh[t - off] : 0;
        __syncthreads();
        sh[t] += a;
        __syncthreads();
    }
    int run = sh[t] - s;
    run += v0; if (base + 0 < Nv) rp[base + 1] = run;
    run += v1; if (base + 1 < Nv) rp[base + 2] = run;
    run += v2; if (base + 2 < Nv) rp[base + 3] = run;
    run += v3; if (base + 3 < Nv) rp[base + 4] = run;
    if (t == 255) bsum[blockIdx.x] = sh[255];
}

__global__ __launch_bounds__(256) void scan2_kernel(int* __restrict__ bsum, int nb) {
    __shared__ int sh[256];
    int t = threadIdx.x;
    int v = (t < nb) ? bsum[t] : 0;
    sh[t] = v;
    __syncthreads();
    for (int off = 1; off < 256; off <<= 1) {
        int a = (t >= off) ? sh[t - off] : 0;
        __syncthreads();
        sh[t] += a;
        __syncthreads();
    }
    if (t < nb) bsum[t] = sh[t] - v;
}

__global__ __launch_bounds__(256) void scan3_kernel(int* __restrict__ rp,
                                                    const int* __restrict__ bsum, int Nv) {
    int i = blockIdx.x * 256 + threadIdx.x;
    if (i == 0) rp[0] = 0;
    if (i < Nv) rp[i + 1] += bsum[i >> 10];
}

__global__ __launch_bounds__(256) void dinv_kernel(const int* __restrict__ deg,
                                                   float* __restrict__ dinv, int Nv) {
    int i = blockIdx.x * 256 + threadIdx.x;
    if (i >= Nv) return;
    int d = deg[i];
    dinv[i] = d > 0 ? rsqrtf((float)d) : 0.f;
}

__global__ __launch_bounds__(256) void scatter_kernel(const int* __restrict__ ei, int E,
                                                      const int* __restrict__ rp,
                                                      int* __restrict__ fill,
                                                      const float* __restrict__ dinv,
                                                      int2* __restrict__ ce) {
    int e = blockIdx.x * 256 + threadIdx.x;
    if (e >= E) return;
    int r = ei[e], c = ei[E + e];
    if (r == c) return;
    int slot = rp[r] + atomicAdd(&fill[r], 1);
    float w = -dinv[r] * dinv[c];
    ce[slot] = make_int2(c, __float_as_int(w));
}

// ---------- f32 -> bf16 bulk convert ----------

__global__ __launch_bounds__(256) void tobf16_kernel(const float4* __restrict__ src,
                                                     ushort4* __restrict__ dst, int n4) {
    int i = blockIdx.x * 256 + threadIdx.x;
    if (i >= n4) return;
    float4 v = src[i];
    dst[i] = make_ushort4(f2bf(v.x), f2bf(v.y), f2bf(v.z), f2bf(v.w));
}

// ---------- acc = x @ W0 (init) ----------

__global__ __launch_bounds__(256, 4) void mm_init_kernel(const float* __restrict__ X,
                                                         const float* __restrict__ W0,
                                                         float* __restrict__ acc, int Nv) {
    __shared__ float sh[WPB][F];
    int wave = threadIdx.x >> 6, lane = threadIdx.x & 63;
    float wr[F];
#pragma unroll
    for (int j = 0; j < F; j++) wr[j] = W0[j * F + lane];
    for (int r = 0; r < RPW; r++) {
        int i = blockIdx.x * (WPB * RPW) + r * WPB + wave;
        bool act = i < Nv;
        int ii = act ? i : 0;
        float xv = X[(size_t)ii * F + lane];
        sh[wave][lane] = xv;
        __syncthreads();
        float a = 0.f;
        const float4* tb = (const float4*)sh[wave];
#pragma unroll
        for (int j4 = 0; j4 < F / 4; j4++) {
            float4 tv = tb[j4];
            a = fmaf(tv.x, wr[4 * j4 + 0], a);
            a = fmaf(tv.y, wr[4 * j4 + 1], a);
            a = fmaf(tv.z, wr[4 * j4 + 2], a);
            a = fmaf(tv.w, wr[4 * j4 + 3], a);
        }
        if (act) acc[(size_t)i * F + lane] = a;
        __syncthreads();
    }
}

// ---------- fused prop (bf16 gather) + recurrence + acc += tk @ Wk ----------
// Phase A: each wave computes tk for its 16 contiguous rows (8-deep gather
// chains), stores to LDS + global (f32 for future Tm2, bf16 for next gather).
// One __syncthreads. Phase B: per-row micro-GEMM from LDS vs register Wk col.

__global__ __launch_bounds__(256, 4) void prop_mm_v2(const ushort* __restrict__ Tm1h,
                                                     const float* __restrict__ Tm2,
                                                     float* __restrict__ Tout,
                                                     ushort* __restrict__ Touth,
                                                     const int* __restrict__ rp,
                                                     const int2* __restrict__ ce,
                                                     const float* __restrict__ Wk,
                                                     float* __restrict__ acc,
                                                     int Nv, int first,
                                                     int store_f, int store_h) {
    __shared__ float tkb[WPB * RPW][F];
    int wave = threadIdx.x >> 6, lane = threadIdx.x & 63;
    int rbase = blockIdx.x * (WPB * RPW) + wave * RPW;

    // ---- phase A ----
    for (int r = 0; r < RPW; r++) {
        int i = rbase + r;
        bool act = i < Nv;
        int ii = act ? i : 0;
        int s = rp[ii], e = rp[ii + 1];
        float s0 = 0.f, s1 = 0.f, s2 = 0.f, s3 = 0.f;
        float s4 = 0.f, s5 = 0.f, s6 = 0.f, s7 = 0.f;
        int p = s;
        for (; p + 8 <= e; p += 8) {
            int2 c0 = ce[p + 0], c1 = ce[p + 1], c2 = ce[p + 2], c3 = ce[p + 3];
            int2 c4 = ce[p + 4], c5 = ce[p + 5], c6 = ce[p + 6], c7 = ce[p + 7];
            s0 = fmaf(__int_as_float(c0.y), bf2f(Tm1h[(size_t)c0.x * F + lane]), s0);
            s1 = fmaf(__int_as_float(c1.y), bf2f(Tm1h[(size_t)c1.x * F + lane]), s1);
            s2 = fmaf(__int_as_float(c2.y), bf2f(Tm1h[(size_t)c2.x * F + lane]), s2);
            s3 = fmaf(__int_as_float(c3.y), bf2f(Tm1h[(size_t)c3.x * F + lane]), s3);
            s4 = fmaf(__int_as_float(c4.y), bf2f(Tm1h[(size_t)c4.x * F + lane]), s4);
            s5 = fmaf(__int_as_float(c5.y), bf2f(Tm1h[(size_t)c5.x * F + lane]), s5);
            s6 = fmaf(__int_as_float(c6.y), bf2f(Tm1h[(size_t)c6.x * F + lane]), s6);
            s7 = fmaf(__int_as_float(c7.y), bf2f(Tm1h[(size_t)c7.x * F + lane]), s7);
        }
        for (; p < e; p++) {
            int2 c0 = ce[p];
            s0 = fmaf(__int_as_float(c0.y), bf2f(Tm1h[(size_t)c0.x * F + lane]), s0);
        }
        float sum = ((s0 + s1) + (s2 + s3)) + ((s4 + s5) + (s6 + s7));
        float tk = first ? sum : fmaf(2.f, sum, -Tm2[(size_t)ii * F + lane]);
        tkb[wave * RPW + r][lane] = tk;
        if (act) {
            if (store_f) Tout[(size_t)i * F + lane] = tk;
            if (store_h) Touth[(size_t)i * F + lane] = f2bf(tk);
        }
    }
    __syncthreads();

    // ---- phase B ----
    float wr[F];
#pragma unroll
    for (int j = 0; j < F; j++) wr[j] = Wk[j * F + lane];  // column `lane` of Wk
    for (int r = 0; r < RPW; r++) {
        int i = rbase + r;
        if (i >= Nv) break;
        const float4* tb = (const float4*)tkb[wave * RPW + r];
        float a2 = 0.f;
#pragma unroll
        for (int j4 = 0; j4 < F / 4; j4++) {
            float4 tv = tb[j4];
            a2 = fmaf(tv.x, wr[4 * j4 + 0], a2);
            a2 = fmaf(tv.y, wr[4 * j4 + 1], a2);
            a2 = fmaf(tv.z, wr[4 * j4 + 2], a2);
            a2 = fmaf(tv.w, wr[4 * j4 + 3], a2);
        }
        acc[(size_t)i * F + lane] += a2;
    }
}

// ---------- bias + LayerNorm + ELU (in place on d_out) ----------

__global__ __launch_bounds__(256) void ln_elu_kernel(float* __restrict__ io,
                                                     const float* __restrict__ bias,
                                                     const float* __restrict__ lnw,
                                                     const float* __restrict__ lnb, int Nv) {
    int wave = threadIdx.x >> 6, lane = threadIdx.x & 63;
    int i = blockIdx.x * WPB + wave;
    if (i >= Nv) return;
    float v = io[(size_t)i * F + lane] + bias[lane];
    float s = v;
#pragma unroll
    for (int off = 1; off < 64; off <<= 1) s += __shfl_xor(s, off, 64);
    float mu = s * (1.f / F);
    float d = v - mu;
    float q = d * d;
#pragma unroll
    for (int off = 1; off < 64; off <<= 1) q += __shfl_xor(q, off, 64);
    float y = d * rsqrtf(q * (1.f / F) + 1e-5f) * lnw[lane] + lnb[lane];
    io[(size_t)i * F + lane] = y > 0.f ? y : expm1f(y);
}

// ---------- host ----------

extern "C" void kernel_launch(void* const* d_in, const int* in_sizes, int n_in,
                              void* d_out, int out_size, void* d_ws, size_t ws_size,
                              hipStream_t stream) {
    (void)n_in; (void)out_size;
    const float* x    = (const float*)d_in[0];
    const int*   ei   = (const int*)d_in[1];
    const float* W    = (const float*)d_in[2];
    const float* bias = (const float*)d_in[3];
    const float* lnw  = (const float*)d_in[4];
    const float* lnb  = (const float*)d_in[5];
    float* out = (float*)d_out;

    int Nv = in_sizes[0] / F;
    int E  = in_sizes[1] / 2;
    int K  = in_sizes[2] / (F * F);

    char* base = (char*)d_ws;
    size_t off = 0;
    auto alloc = [&](size_t b) -> void* {
        void* p = base + off;
        off += (b + 255) & ~(size_t)255;
        return p;
    };
    int*    deg  = (int*)alloc((size_t)Nv * 4);
    int*    fill = (int*)alloc((size_t)Nv * 4);
    int*    rp   = (int*)alloc(((size_t)Nv + 1) * 4);
    int     nb   = (Nv + 1023) / 1024;
    int*    bsum = (int*)alloc((size_t)nb * 4);
    float*  dinv = (float*)alloc((size_t)Nv * 4);
    int2*   ce   = (int2*)alloc((size_t)E * 8);
    float*  Ta   = (float*)alloc((size_t)Nv * F * 4);
    float*  Tb   = (float*)alloc((size_t)Nv * F * 4);
    ushort* xh   = (ushort*)alloc((size_t)Nv * F * 2);
    ushort* Tah  = (ushort*)alloc((size_t)Nv * F * 2);
    ushort* Tbh  = (ushort*)alloc((size_t)Nv * F * 2);
    if (off > ws_size) return;  // ~105 MB required

    hipMemsetAsync(deg, 0, (size_t)Nv * 4, stream);
    hipMemsetAsync(fill, 0, (size_t)Nv * 4, stream);

    int gE = (E + 255) / 256, gN = (Nv + 255) / 256;
    deg_kernel<<<gE, 256, 0, stream>>>(ei, E, deg);
    scan1_kernel<<<nb, 256, 0, stream>>>(deg, rp, bsum, Nv);
    scan2_kernel<<<1, 256, 0, stream>>>(bsum, nb);
    scan3_kernel<<<gN, 256, 0, stream>>>(rp, bsum, Nv);
    dinv_kernel<<<gN, 256, 0, stream>>>(deg, dinv, Nv);
    scatter_kernel<<<gE, 256, 0, stream>>>(ei, E, rp, fill, dinv, ce);

    int n4 = (Nv * F) / 4;
    tobf16_kernel<<<(n4 + 255) / 256, 256, 0, stream>>>((const float4*)x, (ushort4*)xh, n4);

    int rowsPerBlock = WPB * RPW;
    int gR = (Nv + rowsPerBlock - 1) / rowsPerBlock;
    mm_init_kernel<<<gR, 256, 0, stream>>>(x, W, out, Nv);

    const ushort* tm1h = xh;       // bf16 of T_{k-1} (gather source)
    const float*  tm2  = nullptr;  // f32 of T_{k-2}
    const float*  tm1f = x;        // f32 of T_{k-1}
    for (int k = 1; k < K; k++) {
        float*  tof = (k & 1) ? Ta : Tb;
        ushort* toh = (k & 1) ? Tah : Tbh;
        int store_f = (k <= K - 3) ? 1 : 0;  // f32 needed as Tm2 at level k+2
        int store_h = (k <= K - 2) ? 1 : 0;  // bf16 needed as gather src at k+1
        prop_mm_v2<<<gR, 256, 0, stream>>>(tm1h, tm2, tof, toh, rp, ce,
                                           W + (size_t)k * F * F, out, Nv,
                                           k == 1 ? 1 : 0, store_f, store_h);
        tm2  = tm1f;
        tm1f = tof;
        tm1h = toh;
    }

    ln_elu_kernel<<<(Nv + WPB - 1) / WPB, 256, 0, stream>>>(out, bias, lnw, lnb, Nv);
}

// Round 3
// 1299.814 us; speedup vs baseline: 1.5302x; 1.5302x over previous
//
#include <hip/hip_runtime.h>
#include <math.h>

#define F 64

static __device__ __forceinline__ ushort f2bf(float f) {
    uint u = __float_as_uint(f);
    uint r = (u + 0x7fffu + ((u >> 16) & 1u)) >> 16;  // RNE
    return (ushort)r;
}
static __device__ __forceinline__ float bf2f(ushort v) {
    return __uint_as_float(((uint)v) << 16);
}

// ---------- CSR build ----------

__global__ __launch_bounds__(256) void deg_kernel(const int* __restrict__ ei, int E,
                                                  int* __restrict__ deg) {
    int e = blockIdx.x * 256 + threadIdx.x;
    if (e >= E) return;
    int r = ei[e], c = ei[E + e];
    if (r != c) atomicAdd(&deg[r], 1);
}

__global__ __launch_bounds__(256) void scan1_kernel(const int* __restrict__ deg,
                                                    int* __restrict__ rp,
                                                    int* __restrict__ bsum, int Nv) {
    __shared__ int sh[256];
    int t = threadIdx.x;
    int base = blockIdx.x * 1024 + t * 4;
    int v0 = (base + 0 < Nv) ? deg[base + 0] : 0;
    int v1 = (base + 1 < Nv) ? deg[base + 1] : 0;
    int v2 = (base + 2 < Nv) ? deg[base + 2] : 0;
    int v3 = (base + 3 < Nv) ? deg[base + 3] : 0;
    int s = v0 + v1 + v2 + v3;
    sh[t] = s;
    __syncthreads();
    for (int off = 1; off < 256; off <<= 1) {
        int a = (t >= off) ? sh[t - off] : 0;
        __syncthreads();
        sh[t] += a;
        __syncthreads();
    }
    int run = sh[t] - s;
    run += v0; if (base + 0 < Nv) rp[base + 1] = run;
    run += v1; if (base + 1 < Nv) rp[base + 2] = run;
    run += v2; if (base + 2 < Nv) rp[base + 3] = run;
    run += v3; if (base + 3 < Nv) rp[base + 4] = run;
    if (t == 255) bsum[blockIdx.x] = sh[255];
}

__global__ __launch_bounds__(256) void scan2_kernel(int* __restrict__ bsum, int nb) {
    __shared__ int sh[256];
    int t = threadIdx.x;
    int v = (t < nb) ? bsum[t] : 0;
    sh[t] = v;
    __syncthreads();
    for (int off = 1; off < 256; off <<= 1) {
        int a = (t >= off) ? sh[t - off] : 0;
        __syncthreads();
        sh[t] += a;
        __syncthreads();
    }
    if (t < nb) bsum[t] = sh[t] - v;
}

__global__ __launch_bounds__(256) void scan3_kernel(int* __restrict__ rp,
                                                    const int* __restrict__ bsum, int Nv) {
    int i = blockIdx.x * 256 + threadIdx.x;
    if (i == 0) rp[0] = 0;
    if (i < Nv) rp[i + 1] += bsum[i >> 10];
}

__global__ __launch_bounds__(256) void dinv_kernel(const int* __restrict__ deg,
                                                   float* __restrict__ dinv, int Nv) {
    int i = blockIdx.x * 256 + threadIdx.x;
    if (i >= Nv) return;
    int d = deg[i];
    dinv[i] = d > 0 ? rsqrtf((float)d) : 0.f;
}

__global__ __launch_bounds__(256) void scatter_kernel(const int* __restrict__ ei, int E,
                                                      const int* __restrict__ rp,
                                                      int* __restrict__ fill,
                                                      const float* __restrict__ dinv,
                                                      int2* __restrict__ ce) {
    int e = blockIdx.x * 256 + threadIdx.x;
    if (e >= E) return;
    int r = ei[e], c = ei[E + e];
    if (r == c) return;
    int slot = rp[r] + atomicAdd(&fill[r], 1);
    float w = -dinv[r] * dinv[c];
    ce[slot] = make_int2(c, __float_as_int(w));
}

// ---------- f32 -> bf16 bulk convert ----------

__global__ __launch_bounds__(256) void tobf16_kernel(const float4* __restrict__ src,
                                                     ushort4* __restrict__ dst, int n4) {
    int i = blockIdx.x * 256 + threadIdx.x;
    if (i >= n4) return;
    float4 v = src[i];
    dst[i] = make_ushort4(f2bf(v.x), f2bf(v.y), f2bf(v.z), f2bf(v.w));
}

// ---------- lean prop: tk = 2*L_hat@T_{k-1} - T_{k-2} ----------
// 4 rows/wave, 4 waves/block -> 16 rows/block. bf16 gather source, f32
// recurrence. bf16 output packed in LDS, stored cooperatively as uint4
// (one contiguous 2KB segment per block) to avoid sub-sector RMW writes.

#define PR_ROWS 16  // rows per block

__global__ __launch_bounds__(256) void prop_v3(const ushort* __restrict__ Tm1h,
                                               const float* __restrict__ Tm2,
                                               float* __restrict__ Tout,
                                               ushort* __restrict__ Touth,
                                               const int* __restrict__ rp,
                                               const int2* __restrict__ ce,
                                               int Nv, int first, int store_h) {
    __shared__ __align__(16) ushort ush[PR_ROWS][F];
    int wave = threadIdx.x >> 6, lane = threadIdx.x & 63;
    int rbase = blockIdx.x * PR_ROWS + wave * 4;

    for (int r = 0; r < 4; r++) {
        int i = rbase + r;
        bool act = i < Nv;
        int ii = act ? i : 0;
        float tm2 = first ? 0.f : Tm2[(size_t)ii * F + lane];  // prefetch early
        int s = rp[ii], e = rp[ii + 1];
        float s0 = 0.f, s1 = 0.f, s2 = 0.f, s3 = 0.f;
        float s4 = 0.f, s5 = 0.f, s6 = 0.f, s7 = 0.f;
        int p = s;
        for (; p + 8 <= e; p += 8) {  // 8 independent miss chains
            int2 c0 = ce[p + 0], c1 = ce[p + 1], c2 = ce[p + 2], c3 = ce[p + 3];
            int2 c4 = ce[p + 4], c5 = ce[p + 5], c6 = ce[p + 6], c7 = ce[p + 7];
            s0 = fmaf(__int_as_float(c0.y), bf2f(Tm1h[(size_t)c0.x * F + lane]), s0);
            s1 = fmaf(__int_as_float(c1.y), bf2f(Tm1h[(size_t)c1.x * F + lane]), s1);
            s2 = fmaf(__int_as_float(c2.y), bf2f(Tm1h[(size_t)c2.x * F + lane]), s2);
            s3 = fmaf(__int_as_float(c3.y), bf2f(Tm1h[(size_t)c3.x * F + lane]), s3);
            s4 = fmaf(__int_as_float(c4.y), bf2f(Tm1h[(size_t)c4.x * F + lane]), s4);
            s5 = fmaf(__int_as_float(c5.y), bf2f(Tm1h[(size_t)c5.x * F + lane]), s5);
            s6 = fmaf(__int_as_float(c6.y), bf2f(Tm1h[(size_t)c6.x * F + lane]), s6);
            s7 = fmaf(__int_as_float(c7.y), bf2f(Tm1h[(size_t)c7.x * F + lane]), s7);
        }
        for (; p < e; p++) {
            int2 c0 = ce[p];
            s0 = fmaf(__int_as_float(c0.y), bf2f(Tm1h[(size_t)c0.x * F + lane]), s0);
        }
        float sum = ((s0 + s1) + (s2 + s3)) + ((s4 + s5) + (s6 + s7));
        float tk = first ? sum : fmaf(2.f, sum, -tm2);
        if (act) Tout[(size_t)i * F + lane] = tk;  // dword stores: coalesce fine
        ush[wave * 4 + r][lane] = f2bf(tk);
    }
    __syncthreads();
    if (store_h) {
        int t = threadIdx.x;
        if (t < 128) {  // 16 rows * 128B = 2KB = 128 uint4, contiguous in global
            int row = t >> 3;  // 8 uint4 per row
            if (blockIdx.x * PR_ROWS + row < Nv) {
                uint4 v = ((const uint4*)ush)[t];
                ((uint4*)Touth)[(size_t)blockIdx.x * 128 + t] = v;
            }
        }
    }
}

// ---------- dense: acc (=|+=) T @ Wk, W register-resident ----------

__global__ __launch_bounds__(256) void dense_mm(const float* __restrict__ T,
                                                const float* __restrict__ Wk,
                                                float* __restrict__ acc,
                                                int Nv, int rmw) {
    int wave = threadIdx.x >> 6, lane = threadIdx.x & 63;
    float wr[F];
#pragma unroll
    for (int j = 0; j < F; j++) wr[j] = Wk[j * F + lane];  // column `lane`
    int gw = blockIdx.x * 4 + wave;
    int nw = gridDim.x * 4;
    for (int i = gw; i < Nv; i += nw) {
        float tv = T[(size_t)i * F + lane];
        float a = 0.f;
#pragma unroll
        for (int j = 0; j < F; j++)
            a = fmaf(__shfl(tv, j, 64), wr[j], a);  // readlane broadcast
        if (rmw) acc[(size_t)i * F + lane] += a;
        else     acc[(size_t)i * F + lane] = a;
    }
}

// ---------- bias + LayerNorm + ELU (in place on d_out) ----------

__global__ __launch_bounds__(256) void ln_elu_kernel(float* __restrict__ io,
                                                     const float* __restrict__ bias,
                                                     const float* __restrict__ lnw,
                                                     const float* __restrict__ lnb, int Nv) {
    int wave = threadIdx.x >> 6, lane = threadIdx.x & 63;
    int i = blockIdx.x * 4 + wave;
    if (i >= Nv) return;
    float v = io[(size_t)i * F + lane] + bias[lane];
    float s = v;
#pragma unroll
    for (int off = 1; off < 64; off <<= 1) s += __shfl_xor(s, off, 64);
    float mu = s * (1.f / F);
    float d = v - mu;
    float q = d * d;
#pragma unroll
    for (int off = 1; off < 64; off <<= 1) q += __shfl_xor(q, off, 64);
    float y = d * rsqrtf(q * (1.f / F) + 1e-5f) * lnw[lane] + lnb[lane];
    io[(size_t)i * F + lane] = y > 0.f ? y : expm1f(y);
}

// ---------- host ----------

extern "C" void kernel_launch(void* const* d_in, const int* in_sizes, int n_in,
                              void* d_out, int out_size, void* d_ws, size_t ws_size,
                              hipStream_t stream) {
    (void)n_in; (void)out_size;
    const float* x    = (const float*)d_in[0];
    const int*   ei   = (const int*)d_in[1];
    const float* W    = (const float*)d_in[2];
    const float* bias = (const float*)d_in[3];
    const float* lnw  = (const float*)d_in[4];
    const float* lnb  = (const float*)d_in[5];
    float* out = (float*)d_out;

    int Nv = in_sizes[0] / F;
    int E  = in_sizes[1] / 2;
    int K  = in_sizes[2] / (F * F);

    char* base = (char*)d_ws;
    size_t off = 0;
    auto alloc = [&](size_t b) -> void* {
        void* p = base + off;
        off += (b + 255) & ~(size_t)255;
        return p;
    };
    int*    deg  = (int*)alloc((size_t)Nv * 4);
    int*    fill = (int*)alloc((size_t)Nv * 4);
    int*    rp   = (int*)alloc(((size_t)Nv + 1) * 4);
    int     nb   = (Nv + 1023) / 1024;
    int*    bsum = (int*)alloc((size_t)nb * 4);
    float*  dinv = (float*)alloc((size_t)Nv * 4);
    int2*   ce   = (int2*)alloc((size_t)E * 8);
    float*  Ta   = (float*)alloc((size_t)Nv * F * 4);
    float*  Tb   = (float*)alloc((size_t)Nv * F * 4);
    ushort* xh   = (ushort*)alloc((size_t)Nv * F * 2 + 2048);  // +pad for uint4 tail
    ushort* Tah  = (ushort*)alloc((size_t)Nv * F * 2 + 2048);
    ushort* Tbh  = (ushort*)alloc((size_t)Nv * F * 2 + 2048);
    if (off > ws_size) return;  // ~105 MB required

    hipMemsetAsync(deg, 0, (size_t)Nv * 4, stream);
    hipMemsetAsync(fill, 0, (size_t)Nv * 4, stream);

    int gE = (E + 255) / 256, gN = (Nv + 255) / 256;
    deg_kernel<<<gE, 256, 0, stream>>>(ei, E, deg);
    scan1_kernel<<<nb, 256, 0, stream>>>(deg, rp, bsum, Nv);
    scan2_kernel<<<1, 256, 0, stream>>>(bsum, nb);
    scan3_kernel<<<gN, 256, 0, stream>>>(rp, bsum, Nv);
    dinv_kernel<<<gN, 256, 0, stream>>>(deg, dinv, Nv);
    scatter_kernel<<<gE, 256, 0, stream>>>(ei, E, rp, fill, dinv, ce);

    int n4 = (Nv * F) / 4;
    tobf16_kernel<<<(n4 + 255) / 256, 256, 0, stream>>>((const float4*)x, (ushort4*)xh, n4);

    // acc = x @ W0
    dense_mm<<<1024, 256, 0, stream>>>(x, W, out, Nv, 0);

    int gP = (Nv + PR_ROWS - 1) / PR_ROWS;
    const ushort* tm1h = xh;
    for (int k = 1; k < K; k++) {
        float*  tof = (k & 1) ? Ta : Tb;          // T_k f32
        ushort* toh = (k & 1) ? Tah : Tbh;        // T_k bf16
        // Tm2 f32: k==1 none; k==2 x; k>=3 same buffer as tof (in-place safe)
        const float* tm2 = (k == 1) ? nullptr : (k == 2) ? x : (const float*)tof;
        int store_h = (k <= K - 2) ? 1 : 0;
        prop_v3<<<gP, 256, 0, stream>>>(tm1h, tm2, tof, toh, rp, ce, Nv,
                                        k == 1 ? 1 : 0, store_h);
        dense_mm<<<1024, 256, 0, stream>>>(tof, W + (size_t)k * F * F, out, Nv, 1);
        tm1h = toh;
    }

    ln_elu_kernel<<<(Nv + 3) / 4, 256, 0, stream>>>(out, bias, lnw, lnb, Nv);
}